// Round 4
// baseline (126.669 us; speedup 1.0000x reference)
//
#include <hip/hip_runtime.h>
#include <math.h>

#define NSAMP 32768
#define FS_F 44100.0f
#define PI_F 3.14159265358979323846f
#define T1 1024  // KS slice length (32 slices/batch)
#define FLAG_MAGIC 0x5A5A5A5A

// LDS layout (floats, dynamic):
//   xall [0, 33536)      whole-span preLP'd excitation (KS input)
//   lws  [33536, 33568)  segment totals for the prologue scan
//   tabs [33568, 40480)  body tables (bandc/Qlev/Qw/Rtab)
// body overlays: sl = [0,5376), body lws/lc0/lc1 at [6144..6248)
#define XCAP 33536
#define LWS_OFF 33536
#define TABS_OFF 33568
#define SMEM_FLOATS 40480  // 161920 bytes

struct BParams {
  float alpha, alpha_p;
  float fr, g, s;
  int Di;
  float lc, lm, lp;
};

__device__ inline float sigmoidf_(float x) { return 1.0f / (1.0f + expf(-x)); }

__device__ inline BParams compute_params(int b, const float* __restrict__ pitch,
                                         const float* __restrict__ w1,
                                         const float* __restrict__ b1,
                                         const float* __restrict__ w2,
                                         const float* __restrict__ b2) {
  BParams P;
  float p = pitch[b];
  float h[16];
#pragma unroll
  for (int i = 0; i < 16; ++i) {
    float v = fmaf(p, w1[i], b1[i]);
    h[i] = v > 0.0f ? v : 0.0f;
  }
  float m[3];
#pragma unroll
  for (int j = 0; j < 3; ++j) {
    float acc = b2[j];
#pragma unroll
    for (int i = 0; i < 16; ++i) acc = fmaf(h[i], w2[j * 16 + i], acc);
    m[j] = acc;
  }
  P.lc = fminf(fmaxf(m[0], -2.0f), 2.5f);
  P.lm = fminf(fmaxf(m[1], -2.5f), 0.0f);
  P.lp = fminf(fmaxf(m[2], -4.0f), 4.0f);
  P.g = 0.999f * sigmoidf_(P.lc);
  P.s = sigmoidf_(P.lm);
  float f0 = fmaxf(p, 60.0f);
  float D = fminf(fmaxf(FS_F / f0, 2.0f), 735.0f);
  int Di = (int)floorf(D);
  P.fr = D - (float)Di;
  P.Di = Di;
  float mult = fminf(fmaxf(2.0f + 6.0f * (f0 - 60.0f) / 600.0f, 2.0f), 8.0f);
  float cutoff = fminf(2.0f * PI_F * f0 * mult / FS_F, PI_F * 0.9f);
  P.alpha = 1.0f - expf(-cutoff);
  float cpost = fminf(PI_F * sigmoidf_(P.lp), PI_F * 0.99f);
  P.alpha_p = 1.0f - expf(-cpost);
  return P;
}

// lane helpers (wave64)
__device__ inline float rlv(float v, int l) {
  return __int_as_float(__builtin_amdgcn_readlane(__float_as_int(v), l));
}
__device__ inline float shr1(float v, float bnd) {
  return __int_as_float(__builtin_amdgcn_update_dpp(
      __float_as_int(bnd), __float_as_int(v), 0x138 /*wave_shr:1*/, 0xf, 0xf,
      false));
}
// rotate right by 1: lane0 <- lane63
__device__ inline float ror1(float v) {
  return __int_as_float(__builtin_amdgcn_update_dpp(
      __float_as_int(v), __float_as_int(v), 0x13C /*wave_ror:1*/, 0xf, 0xf,
      false));
}

__device__ inline void band_coef(int k, float& a1, float& a2, float& b0) {
  float fc = 80.0f * exp2f((float)k * (6.64385618977472436f / 23.0f));
  float w = 2.0f * PI_F * fc / FS_F;
  float r = expf(-PI_F * fc / (10.0f * FS_F));
  a1 = -2.0f * r * cosf(w);
  a2 = r * r;
  b0 = 1.0f - r;
}

// ---- data-independent body tables (verified bit-exact vs in-body compute) --
__device__ inline void gen_tables(float* __restrict__ tabs, int W) {
  if (W >= 120) return;
  const int j = W / 5, sub = W % 5;
  float A1, A2, B0;
  band_coef(j, A1, A2, B0);
  if (sub == 0) *(float4*)&tabs[j * 4] = make_float4(A1, A2, B0, 0.f);
  float Q00 = -A1, Q01 = -A2, Q10 = 1.f, Q11 = 0.f;
#pragma unroll
  for (int sq = 0; sq < 2; ++sq) {
    float n00 = fmaf(Q00, Q00, Q01 * Q10);
    float n01 = fmaf(Q00, Q01, Q01 * Q11);
    float n10 = fmaf(Q10, Q00, Q11 * Q10);
    float n11 = fmaf(Q10, Q01, Q11 * Q11);
    Q00 = n00; Q01 = n01; Q10 = n10; Q11 = n11;
  }
  float K00 = Q00, K01 = Q01, K10 = Q10, K11 = Q11;
#pragma unroll
  for (int sq = 0; sq < 2; ++sq) {
    float n00 = fmaf(Q00, Q00, Q01 * Q10);
    float n01 = fmaf(Q00, Q01, Q01 * Q11);
    float n10 = fmaf(Q10, Q00, Q11 * Q10);
    float n11 = fmaf(Q10, Q01, Q11 * Q11);
    Q00 = n00; Q01 = n01; Q10 = n10; Q11 = n11;
  }
  float L00[7], L01[7], L10[7], L11[7];
  L00[0] = fmaf(Q00, K00, Q01 * K10);
  L01[0] = fmaf(Q00, K01, Q01 * K11);
  L10[0] = fmaf(Q10, K00, Q11 * K10);
  L11[0] = fmaf(Q10, K01, Q11 * K11);
#pragma unroll
  for (int k = 0; k < 6; ++k) {
    float s00 = fmaf(L00[k], L00[k], L01[k] * L10[k]);
    float s01 = fmaf(L00[k], L01[k], L01[k] * L11[k]);
    float s10 = fmaf(L10[k], L00[k], L11[k] * L10[k]);
    float s11 = fmaf(L10[k], L01[k], L11[k] * L11[k]);
    L00[k + 1] = s00; L01[k + 1] = s01; L10[k + 1] = s10; L11[k + 1] = s11;
  }
  if (sub == 0) {
#pragma unroll
    for (int k = 0; k < 6; ++k)
      *(float4*)&tabs[96 + (k * 24 + j) * 4] =
          make_float4(L00[k], L01[k], L10[k], L11[k]);
    *(float4*)&tabs[672 + j * 4] = make_float4(L00[6], L01[6], L10[6], L11[6]);
  }
  int l0 = sub * 13, l1 = l0 + 13;
  if (l1 > 64) l1 = 64;
  for (int l = l0; l < l1; ++l) {
    float R00 = 1.f, R01 = 0.f, R10 = 0.f, R11 = 1.f;
#pragma unroll
    for (int bit = 0; bit < 6; ++bit) {
      if ((l >> bit) & 1) {
        float n00 = fmaf(L00[bit], R00, L01[bit] * R10);
        float n01 = fmaf(L00[bit], R01, L01[bit] * R11);
        float n10 = fmaf(L10[bit], R00, L11[bit] * R10);
        float n11 = fmaf(L10[bit], R01, L11[bit] * R11);
        R00 = n00; R01 = n01; R10 = n10; R11 = n11;
      }
    }
    *(float4*)&tabs[768 + (j * 64 + l) * 4] = make_float4(R00, R01, R10, R11);
  }
}

// ---- single-wave KS recurrence (wave 0), barrier-free, x fully in LDS ----
template <int KNUM>
__device__ void ks_wave0(float* __restrict__ yg, const float* xall, int lane,
                         int C, float c0w, float c1w, float c2w, int s1,
                         int n0, int end, int span) {
  const int lq1 = (C - 1) - (KNUM - 1) * 64;
  const int W = n0 - s1;
  float yp[KNUM], xC[KNUM], xN[KNUM];
  float p1 = 0.f, p2 = 0.f;
#pragma unroll
  for (int k = 0; k < KNUM; ++k) {
    yp[k] = 0.f;
    xC[k] = xall[lane + (k << 6)];
    xN[k] = xall[C + lane + (k << 6)];
  }
  int rel = 0;
  while (rel + C <= W) {  // lean warm-up (no stores)
    float b2v[KNUM], b3v[KNUM];
    b2v[0] = shr1(yp[0], p1);
#pragma unroll
    for (int k = 1; k < KNUM; ++k) b2v[k] = shr1(yp[k], ror1(yp[k - 1]));
    b3v[0] = shr1(b2v[0], p2);
#pragma unroll
    for (int k = 1; k < KNUM; ++k) b3v[k] = shr1(b2v[k], ror1(b2v[k - 1]));
    float p1n = rlv(yp[KNUM - 1], lq1);
    float p2n = rlv(b2v[KNUM - 1], lq1);
#pragma unroll
    for (int k = 0; k < KNUM; ++k)
      yp[k] = fmaf(c0w, yp[k], fmaf(c2w, b3v[k], fmaf(c1w, b2v[k], xC[k])));
    p1 = p1n;
    p2 = p2n;
    int r2 = rel + 2 * C;
    if (r2 < span) {
      const float* xp = &xall[r2 + lane];
#pragma unroll
      for (int k = 0; k < KNUM; ++k) {
        xC[k] = xN[k];
        xN[k] = xp[k << 6];
      }
    } else {
#pragma unroll
      for (int k = 0; k < KNUM; ++k) xC[k] = xN[k];
    }
    rel += C;
  }
  while (rel < span) {  // live region (stores)
    float b2v[KNUM], b3v[KNUM];
    b2v[0] = shr1(yp[0], p1);
#pragma unroll
    for (int k = 1; k < KNUM; ++k) b2v[k] = shr1(yp[k], ror1(yp[k - 1]));
    b3v[0] = shr1(b2v[0], p2);
#pragma unroll
    for (int k = 1; k < KNUM; ++k) b3v[k] = shr1(b2v[k], ror1(b2v[k - 1]));
    float p1n = rlv(yp[KNUM - 1], lq1);
    float p2n = rlv(b2v[KNUM - 1], lq1);
#pragma unroll
    for (int k = 0; k < KNUM; ++k)
      yp[k] = fmaf(c0w, yp[k], fmaf(c2w, b3v[k], fmaf(c1w, b2v[k], xC[k])));
    p1 = p1n;
    p2 = p2n;
#pragma unroll
    for (int k = 0; k < KNUM; ++k) {
      int i = lane + (k << 6);
      int n = s1 + rel + i;
      bool okl = (k < KNUM - 1) || (lane <= lq1);
      if (okl && n >= n0 && n < end) yg[n] = yp[k];
    }
    int r2 = rel + 2 * C;
    if (r2 < span) {
      const float* xp = &xall[r2 + lane];
#pragma unroll
      for (int k = 0; k < KNUM; ++k) {
        xC[k] = xN[k];
        xN[k] = xp[k << 6];
      }
    } else {
#pragma unroll
      for (int k = 0; k < KNUM; ++k) xC[k] = xN[k];
    }
    rel += C;
  }
}

// ---- KS phase: (1) two-pass parallel preLP scan of the WHOLE span into LDS,
// (2) wave0 free-runs the recurrence with zero barriers; waves 2-3 generate
// body tables meanwhile. ----
__device__ inline void ks_phase(int b, int q, const BParams& P,
                                const float* __restrict__ exc, float scale0,
                                float* __restrict__ buf1, float* xall,
                                float* lws, float* tabs, int t) {
  const int C = P.Di;
  const int n0 = q << 10;
  float lg = -logf(P.g);
  int Wp = (int)ceilf(10.5f / fmaxf(lg, 1e-6f));
  if (Wp > 64) Wp = 64;
  if (Wp < 4) Wp = 4;
  int W = Wp * C;
  if (W > n0) W = n0;
  W = (W + 3) & ~3;
  const int s1 = n0 - W;
  const int span = W + T1;
  const int end = n0 + T1;
  const int NSG = (span + 2047) >> 11;  // segments covering span, <= 16
  float* yg = buf1 + (size_t)b * NSAMP;
  const float* xg = exc + (size_t)b * NSAMP;

  const float c = 1.0f - P.alpha;
  const float scale = scale0 * P.alpha;
  const float c2v = c * c, c4 = c2v * c2v, c8 = c4 * c4, c16 = c8 * c8;
  const float c32 = c16 * c16, c64 = c32 * c32, c128 = c64 * c64;
  const float c256 = c128 * c128, c512 = c256 * c256, c1024 = c512 * c512;
  const float c2048 = c1024 * c1024;
  const int lane = t & 63, wid = t >> 6;
  const float c32lane = exp2f((float)(lane << 5) * log2f(c));

  // ---- pass 1: per-segment local scans (segment sg = si-1; si=0 is the
  // vrun pre-warm segment [s1-2048, s1), totals only) ----
  for (int r = 0; r < 5; ++r) {
    int si = r * 4 + wid;
    if (si > NSG) break;
    int sg = si - 1;
    int gbase = s1 + (sg << 11) + (lane << 5);
    float4 pf[8];
#pragma unroll
    for (int i = 0; i < 8; ++i) {
      int g = gbase + 4 * i;
      float4 v = make_float4(0.f, 0.f, 0.f, 0.f);
      if (g >= 0 && g + 3 < NSAMP) v = *(const float4*)&xg[g];
      pf[i] = v;
    }
    float S = 0.0f;
#pragma unroll
    for (int i = 0; i < 8; ++i) {
      S = fmaf(c, S, scale * pf[i].x);
      S = fmaf(c, S, scale * pf[i].y);
      S = fmaf(c, S, scale * pf[i].z);
      S = fmaf(c, S, scale * pf[i].w);
    }
    float Sw = S, u;
    u = __shfl_up(Sw, 1);  if (lane >= 1)  Sw = fmaf(c32, u, Sw);
    u = __shfl_up(Sw, 2);  if (lane >= 2)  Sw = fmaf(c64, u, Sw);
    u = __shfl_up(Sw, 4);  if (lane >= 4)  Sw = fmaf(c128, u, Sw);
    u = __shfl_up(Sw, 8);  if (lane >= 8)  Sw = fmaf(c256, u, Sw);
    u = __shfl_up(Sw, 16); if (lane >= 16) Sw = fmaf(c512, u, Sw);
    u = __shfl_up(Sw, 32); if (lane >= 32) Sw = fmaf(c1024, u, Sw);
    float tot = rlv(Sw, 63);
    float Sex = __shfl_up(Sw, 1);
    if (lane == 0) Sex = 0.0f;
    if (lane == 0) lws[si] = tot;
    if (sg >= 0) {
      float v = Sex;  // local chain (zero carry; fixed in pass 2)
#pragma unroll
      for (int i = 0; i < 8; ++i) {
        float4 y;
        v = fmaf(c, v, scale * pf[i].x); y.x = v;
        v = fmaf(c, v, scale * pf[i].y); y.y = v;
        v = fmaf(c, v, scale * pf[i].z); y.z = v;
        v = fmaf(c, v, scale * pf[i].w); y.w = v;
        pf[i] = y;
      }
      int o = (sg << 11) + (lane << 5);
#pragma unroll
      for (int i = 0; i < 8; ++i) {  // rotated store order: spread banks
        int ci = (lane + i) & 7;
        *(float4*)&xall[o + 4 * ci] = pf[ci];
      }
    }
  }
  // zero-pad [NSG*2048, +768) so garbage-lane reads are bounded
  if (4 * t < 768) {
    *(float4*)&xall[(NSG << 11) + 4 * t] = make_float4(0.f, 0.f, 0.f, 0.f);
  }
  __syncthreads();
  // ---- pass 2: apply cross-segment carries in place ----
  {
    float p4[8];
    p4[0] = 1.0f;
#pragma unroll
    for (int i = 1; i < 8; ++i) p4[i] = p4[i - 1] * c4;
    for (int r = 0; r < 5; ++r) {
      int si = r * 4 + wid;
      if (si > NSG) break;
      int sg = si - 1;
      if (sg < 0) continue;
      float vr = 0.0f;
      for (int i = 0; i < si; ++i) vr = fmaf(c2048, vr, lws[i]);
      float corr0 = c * (c32lane * vr);
      int o = (sg << 11) + (lane << 5);
#pragma unroll
      for (int i = 0; i < 8; ++i) {  // rotated RMW order
        int ci = (lane + i) & 7;
        float4 y = *(float4*)&xall[o + 4 * ci];
        float f = corr0 * p4[ci];
        y.x += f; f *= c;
        y.y += f; f *= c;
        y.z += f; f *= c;
        y.w += f;
        *(float4*)&xall[o + 4 * ci] = y;
      }
    }
  }
  __syncthreads();

  // ---- KS on wave 0 (no barriers); tables on waves 2-3 ----
  const float c0w = P.g * (1.0f - P.s) * (1.0f - P.fr);
  const float c1w = P.g * ((1.0f - P.s) * P.fr + P.s * (1.0f - P.fr));
  const float c2w = P.g * P.s * P.fr;
  if (wid == 0) {
    switch ((C + 63) >> 6) {
      case 2:  ks_wave0<2>(yg, xall, lane, C, c0w, c1w, c2w, s1, n0, end, span); break;
      case 3:  ks_wave0<3>(yg, xall, lane, C, c0w, c1w, c2w, s1, n0, end, span); break;
      case 4:  ks_wave0<4>(yg, xall, lane, C, c0w, c1w, c2w, s1, n0, end, span); break;
      case 5:  ks_wave0<5>(yg, xall, lane, C, c0w, c1w, c2w, s1, n0, end, span); break;
      case 6:  ks_wave0<6>(yg, xall, lane, C, c0w, c1w, c2w, s1, n0, end, span); break;
      case 7:  ks_wave0<7>(yg, xall, lane, C, c0w, c1w, c2w, s1, n0, end, span); break;
      case 8:  ks_wave0<8>(yg, xall, lane, C, c0w, c1w, c2w, s1, n0, end, span); break;
      case 9:  ks_wave0<9>(yg, xall, lane, C, c0w, c1w, c2w, s1, n0, end, span); break;
      case 10: ks_wave0<10>(yg, xall, lane, C, c0w, c1w, c2w, s1, n0, end, span); break;
      case 11: ks_wave0<11>(yg, xall, lane, C, c0w, c1w, c2w, s1, n0, end, span); break;
      default: ks_wave0<12>(yg, xall, lane, C, c0w, c1w, c2w, s1, n0, end, span); break;
    }
  } else if (wid >= 2) {
    gen_tables(tabs, (wid - 2) * 64 + lane);
  }
}

// One-pole scan over [s2, s2+nt*2048) from global into LDS sl[n-s2], reads
// clamped at `lim`.
__device__ inline void lpc_lds(const float* __restrict__ xg,
                               float* __restrict__ sl, int s2, int nt, int lim,
                               float scale, float c, int t, float* lws) {
  const int lane = t & 63, wid = t >> 6;
  float c2v = c * c, c4 = c2v * c2v, c8 = c4 * c4;
  float m1 = c8, m2 = m1 * m1, m4 = m2 * m2, m8 = m4 * m4, m16 = m8 * m8,
        m32 = m16 * m16;
  float c512 = m32 * m32;
  float c2048 = c512 * c512;
  c2048 *= c2048;
  float l2c = log2f(c);
  float c8lane = exp2f((float)(8 * lane) * l2c);
  float cgk = exp2f((float)(8 * t) * l2c);
  float vrun = 0.0f;
  for (int tile = 0; tile < nt; ++tile) {
    __syncthreads();
    int g0 = s2 + (tile << 11) + 8 * t;
    float4 xa = make_float4(0.f, 0.f, 0.f, 0.f);
    float4 xb = make_float4(0.f, 0.f, 0.f, 0.f);
    if (g0 + 3 < lim) xa = *(const float4*)&xg[g0];
    if (g0 + 7 < lim) xb = *(const float4*)&xg[g0 + 4];
    float S = 0.0f;
    S = fmaf(c, S, scale * xa.x); S = fmaf(c, S, scale * xa.y);
    S = fmaf(c, S, scale * xa.z); S = fmaf(c, S, scale * xa.w);
    S = fmaf(c, S, scale * xb.x); S = fmaf(c, S, scale * xb.y);
    S = fmaf(c, S, scale * xb.z); S = fmaf(c, S, scale * xb.w);
    float Sw = S, u;
    u = __shfl_up(Sw, 1);  if (lane >= 1)  Sw = fmaf(m1, u, Sw);
    u = __shfl_up(Sw, 2);  if (lane >= 2)  Sw = fmaf(m2, u, Sw);
    u = __shfl_up(Sw, 4);  if (lane >= 4)  Sw = fmaf(m4, u, Sw);
    u = __shfl_up(Sw, 8);  if (lane >= 8)  Sw = fmaf(m8, u, Sw);
    u = __shfl_up(Sw, 16); if (lane >= 16) Sw = fmaf(m16, u, Sw);
    u = __shfl_up(Sw, 32); if (lane >= 32) Sw = fmaf(m32, u, Sw);
    if (lane == 63) lws[wid] = Sw;
    __syncthreads();
    float a0 = lws[0], a1w = lws[1], a2w = lws[2], a3w = lws[3];
    float carry = (wid == 1)   ? a0
                  : (wid == 2) ? fmaf(c512, a0, a1w)
                  : (wid == 3) ? fmaf(c512, fmaf(c512, a0, a1w), a2w)
                               : 0.0f;
    float Sprev = __shfl_up(Sw, 1);
    float Sex = (lane == 0) ? 0.0f : Sprev;
    Sex = fmaf(c8lane, carry, Sex);
    float v = fmaf(cgk, vrun, Sex);
    int o = g0 - s2;
    float4 ya, yb;
    v = fmaf(c, v, scale * xa.x); ya.x = v;
    v = fmaf(c, v, scale * xa.y); ya.y = v;
    v = fmaf(c, v, scale * xa.z); ya.z = v;
    v = fmaf(c, v, scale * xa.w); ya.w = v;
    v = fmaf(c, v, scale * xb.x); yb.x = v;
    v = fmaf(c, v, scale * xb.y); yb.y = v;
    v = fmaf(c, v, scale * xb.z); yb.z = v;
    v = fmaf(c, v, scale * xb.w); yb.w = v;
    *(float4*)&sl[o] = ya;
    *(float4*)&sl[o + 4] = yb;
    float tS = fmaf(c512, fmaf(c512, fmaf(c512, a0, a1w), a2w), a3w);
    vrun = fmaf(c2048, vrun, tS);
  }
}

// ---- body phase, T2=1024; matrix powers loaded from LDS tables ----
__device__ inline void body_phase(int b, int q, const BParams& P,
                                  const float* __restrict__ gains,
                                  const float* __restrict__ buf1,
                                  float* __restrict__ out, float* sl,
                                  float* lws, float (*lc0)[8],
                                  float (*lc1)[8], const float* tabs, int t) {
  const int lane = t & 63, wid = t >> 6;
  const int n0 = q << 10;
  const int base = n0 - 4096;
  int s2 = base - 256;
  if (s2 < 0) s2 = 0;
  const int end = n0 + 1024;
  const int nt = (end - s2 + 2047) >> 11;  // <= 3

  lpc_lds(buf1 + (size_t)b * NSAMP, sl, s2, nt, end, P.alpha_p,
          1.0f - P.alpha_p, t, lws);
  __syncthreads();

  const float* bandcL = tabs;
  const float* QlevL = tabs + 96;
  const float* QwL = tabs + 672;
  const float* RtabL = tabs + 768;

  const int tb = base + 20 * t;
  float4 acc[5];
#pragma unroll
  for (int i = 0; i < 5; ++i) acc[i] = make_float4(0.f, 0.f, 0.f, 0.f);

  for (int g = 0; g < 3; ++g) {
    float A1[8], A2[8], B0[8], GN[8];
#pragma unroll
    for (int j = 0; j < 8; ++j) {
      int k = g * 8 + j;
      float4 bc = *(const float4*)&bandcL[k * 4];
      A1[j] = bc.x; A2[j] = bc.y; B0[j] = bc.z;
      GN[j] = gains[k];
    }
    float cv0[8], cv1[8];
#pragma unroll
    for (int j = 0; j < 8; ++j) cv0[j] = cv1[j] = 0.f;
    for (int i = 0; i < 5; ++i) {
      int n = tb + 4 * i;
      float4 xv = make_float4(0.f, 0.f, 0.f, 0.f);
      if (n >= 0) xv = *(const float4*)&sl[n - s2];
#pragma unroll
      for (int e = 0; e < 4; ++e) {
        float xi = e == 0 ? xv.x : e == 1 ? xv.y : e == 2 ? xv.z : xv.w;
#pragma unroll
        for (int j = 0; j < 8; ++j) {
          float nc = fmaf(B0[j], xi, -fmaf(A1[j], cv0[j], A2[j] * cv1[j]));
          cv1[j] = cv0[j];
          cv0[j] = nc;
        }
      }
    }
    int kl = 0;
    for (int off = 1; off <= 32; off <<= 1, ++kl) {
      float q00[8], q01[8], q10[8], q11[8];
#pragma unroll
      for (int j = 0; j < 8; ++j) {
        float4 qv = *(const float4*)&QlevL[(kl * 24 + g * 8 + j) * 4];
        q00[j] = qv.x; q01[j] = qv.y; q10[j] = qv.z; q11[j] = qv.w;
      }
#pragma unroll
      for (int j = 0; j < 8; ++j) {
        float u0 = __shfl_up(cv0[j], off);
        float u1 = __shfl_up(cv1[j], off);
        if (lane >= off) {
          float nc0 = fmaf(q00[j], u0, fmaf(q01[j], u1, cv0[j]));
          float nc1 = fmaf(q10[j], u0, fmaf(q11[j], u1, cv1[j]));
          cv0[j] = nc0;
          cv1[j] = nc1;
        }
      }
    }
    __syncthreads();
    if (lane == 63) {
#pragma unroll
      for (int j = 0; j < 8; ++j) {
        lc0[wid][j] = cv0[j];
        lc1[wid][j] = cv1[j];
      }
    }
    __syncthreads();
    float qw00[8], qw01[8], qw10[8], qw11[8];
#pragma unroll
    for (int j = 0; j < 8; ++j) {
      float4 qv = *(const float4*)&QwL[(g * 8 + j) * 4];
      qw00[j] = qv.x; qw01[j] = qv.y; qw10[j] = qv.z; qw11[j] = qv.w;
    }
    float car0[8], car1[8];
#pragma unroll
    for (int j = 0; j < 8; ++j) car0[j] = car1[j] = 0.f;
    for (int v = 0; v < wid; ++v) {
#pragma unroll
      for (int j = 0; j < 8; ++j) {
        float n0c = fmaf(qw00[j], car0[j], fmaf(qw01[j], car1[j], lc0[v][j]));
        float n1c = fmaf(qw10[j], car0[j], fmaf(qw11[j], car1[j], lc1[v][j]));
        car0[j] = n0c;
        car1[j] = n1c;
      }
    }
    float y1[8], y2[8];
#pragma unroll
    for (int j = 0; j < 8; ++j) {
      float4 rv = *(const float4*)&RtabL[((g * 8 + j) * 64 + lane) * 4];
      float e0 = __shfl_up(cv0[j], 1);
      float e1 = __shfl_up(cv1[j], 1);
      if (lane == 0) { e0 = 0.f; e1 = 0.f; }
      y1[j] = fmaf(rv.x, car0[j], fmaf(rv.y, car1[j], e0));
      y2[j] = fmaf(rv.z, car0[j], fmaf(rv.w, car1[j], e1));
    }
    if (tb + 20 > n0) {
      for (int i = 0; i < 5; ++i) {
        float4 xv = *(const float4*)&sl[tb - s2 + 4 * i];
        float4 ov = acc[i];
#pragma unroll
        for (int e = 0; e < 4; ++e) {
          float xi = e == 0 ? xv.x : e == 1 ? xv.y : e == 2 ? xv.z : xv.w;
          float a = 0.f;
#pragma unroll
          for (int j = 0; j < 8; ++j) {
            float yv = fmaf(B0[j], xi, -fmaf(A1[j], y1[j], A2[j] * y2[j]));
            y2[j] = y1[j];
            y1[j] = yv;
            a = fmaf(GN[j], yv, a);
          }
          if (e == 0) ov.x += a;
          else if (e == 1) ov.y += a;
          else if (e == 2) ov.z += a;
          else ov.w += a;
        }
        acc[i] = ov;
      }
    }
  }
  if (tb + 20 > n0) {
    float* outb = out + (size_t)b * NSAMP;
#pragma unroll
    for (int i = 0; i < 5; ++i) {
      int n = tb + 4 * i;
      if (n >= n0) *(float4*)&outb[n] = acc[i];
    }
  }
}

// ======== single kernel, 256 blocks; dynamic LDS 161920 B ========
__global__ void __launch_bounds__(256, 1) synth_all(
    const float* __restrict__ exc, const float* __restrict__ pitch,
    const float* __restrict__ w1, const float* __restrict__ b1,
    const float* __restrict__ w2, const float* __restrict__ b2,
    const float* __restrict__ eg, const float* __restrict__ gains,
    float* __restrict__ buf1, int* __restrict__ flags,
    float* __restrict__ out) {
  extern __shared__ float smem[];
  const int blk = blockIdx.x;
  const int b = blk >> 5, q = blk & 31;
  const int t = threadIdx.x;

  BParams P = compute_params(b, pitch, w1, b1, w2, b2);
  if (blk == 0 && t < 64) {
    int bb = (t < 8) ? t : 0;
    BParams Q = compute_params(bb, pitch, w1, b1, w2, b2);
    float slc = 0.f, slm = 0.f, slp = 0.f;
    for (int i = 0; i < 8; ++i) {
      slc += rlv(Q.lc, i);
      slm += rlv(Q.lm, i);
      slp += rlv(Q.lp, i);
    }
    if (t == 0) {
      out[8 * NSAMP + 0] = slc / 8.0f;
      out[8 * NSAMP + 1] = slm / 8.0f;
      out[8 * NSAMP + 2] = slp / 8.0f;
    }
  }

  // ---- phase 1: KS slice q (writes buf1[n0, n0+1024)); tables generated ----
  ks_phase(b, q, P, exc, eg[0], buf1, smem, smem + LWS_OFF, smem + TABS_OFF, t);
  __syncthreads();  // drain wave0's global stores + table writes

  // ---- handoff: publish own flag, wait for same-batch predecessors ----
  const int n0 = q << 10;
  int s2 = n0 - 4096 - 256;
  if (s2 < 0) s2 = 0;
  const int qlo = s2 >> 10;
  if (t == 0) {
    __hip_atomic_store(&flags[blk], FLAG_MAGIC, __ATOMIC_RELEASE,
                       __HIP_MEMORY_SCOPE_AGENT);
    for (int f = qlo; f < q; ++f) {
      while (__hip_atomic_load(&flags[b * 32 + f], __ATOMIC_ACQUIRE,
                               __HIP_MEMORY_SCOPE_AGENT) != FLAG_MAGIC) {
        __builtin_amdgcn_s_sleep(8);
      }
    }
  }
  __syncthreads();

  // ---- phase 2: body slice q (xall region reused; tables persist) ----
  body_phase(b, q, P, gains, buf1, out, smem, smem + 6144,
             (float(*)[8])(smem + 6152), (float(*)[8])(smem + 6184),
             smem + TABS_OFF, t);
}

extern "C" void kernel_launch(void* const* d_in, const int* in_sizes, int n_in,
                              void* d_out, int out_size, void* d_ws, size_t ws_size,
                              hipStream_t stream) {
  const float* exc = (const float*)d_in[0];
  const float* pitch = (const float*)d_in[1];
  const float* w1 = (const float*)d_in[2];
  const float* b1 = (const float*)d_in[3];
  const float* w2 = (const float*)d_in[4];
  const float* b2 = (const float*)d_in[5];
  const float* eg = (const float*)d_in[6];
  const float* bg = (const float*)d_in[7];
  float* out = (float*)d_out;
  float* buf1 = (float*)d_ws;             // 8*NSAMP floats (KS output)
  int* flags = (int*)(buf1 + 8 * NSAMP);  // 256 flags (poison != MAGIC)

  static int lds_set = 0;
  if (!lds_set) {
    hipFuncSetAttribute(reinterpret_cast<const void*>(synth_all),
                        hipFuncAttributeMaxDynamicSharedMemorySize,
                        SMEM_FLOATS * 4);
    lds_set = 1;
  }
  hipLaunchKernelGGL(synth_all, dim3(256), dim3(256), SMEM_FLOATS * 4, stream,
                     exc, pitch, w1, b1, w2, b2, eg, bg, buf1, flags, out);
}

// Round 5
// 110.719 us; speedup vs baseline: 1.1441x; 1.1441x over previous
//
#include <hip/hip_runtime.h>
#include <math.h>

#define NSAMP 32768
#define FS_F 44100.0f
#define PI_F 3.14159265358979323846f
#define T1 1024  // KS slice length (32 slices/batch)
#define FLAG_MAGIC 0x5A5A5A5A

// LDS layout (floats, dynamic):
//   xall [0, 33536)      whole-span preLP'd excitation (KS input)
//   lws  [33536, 33568)  per-wave partials for the prologue scan
//   tabs [33568, 40480)  body tables (bandc/Qlev/Qw/Rtab)
// body overlays: sl = [0,5376), body lws/lc0/lc1 at [6144..6248)
#define XCAP 33536
#define LWS_OFF 33536
#define TABS_OFF 33568
#define SMEM_FLOATS 40480  // 161920 bytes

struct BParams {
  float alpha, alpha_p;
  float fr, g, s;
  int Di;
  float lc, lm, lp;
};

__device__ inline float sigmoidf_(float x) { return 1.0f / (1.0f + expf(-x)); }

__device__ inline BParams compute_params(int b, const float* __restrict__ pitch,
                                         const float* __restrict__ w1,
                                         const float* __restrict__ b1,
                                         const float* __restrict__ w2,
                                         const float* __restrict__ b2) {
  BParams P;
  float p = pitch[b];
  float h[16];
#pragma unroll
  for (int i = 0; i < 16; ++i) {
    float v = fmaf(p, w1[i], b1[i]);
    h[i] = v > 0.0f ? v : 0.0f;
  }
  float m[3];
#pragma unroll
  for (int j = 0; j < 3; ++j) {
    float acc = b2[j];
#pragma unroll
    for (int i = 0; i < 16; ++i) acc = fmaf(h[i], w2[j * 16 + i], acc);
    m[j] = acc;
  }
  P.lc = fminf(fmaxf(m[0], -2.0f), 2.5f);
  P.lm = fminf(fmaxf(m[1], -2.5f), 0.0f);
  P.lp = fminf(fmaxf(m[2], -4.0f), 4.0f);
  P.g = 0.999f * sigmoidf_(P.lc);
  P.s = sigmoidf_(P.lm);
  float f0 = fmaxf(p, 60.0f);
  float D = fminf(fmaxf(FS_F / f0, 2.0f), 735.0f);
  int Di = (int)floorf(D);
  P.fr = D - (float)Di;
  P.Di = Di;
  float mult = fminf(fmaxf(2.0f + 6.0f * (f0 - 60.0f) / 600.0f, 2.0f), 8.0f);
  float cutoff = fminf(2.0f * PI_F * f0 * mult / FS_F, PI_F * 0.9f);
  P.alpha = 1.0f - expf(-cutoff);
  float cpost = fminf(PI_F * sigmoidf_(P.lp), PI_F * 0.99f);
  P.alpha_p = 1.0f - expf(-cpost);
  return P;
}

// lane helpers (wave64)
__device__ inline float rlv(float v, int l) {
  return __int_as_float(__builtin_amdgcn_readlane(__float_as_int(v), l));
}
__device__ inline float shr1(float v, float bnd) {
  return __int_as_float(__builtin_amdgcn_update_dpp(
      __float_as_int(bnd), __float_as_int(v), 0x138 /*wave_shr:1*/, 0xf, 0xf,
      false));
}
// rotate right by 1: lane0 <- lane63
__device__ inline float ror1(float v) {
  return __int_as_float(__builtin_amdgcn_update_dpp(
      __float_as_int(v), __float_as_int(v), 0x13C /*wave_ror:1*/, 0xf, 0xf,
      false));
}

// Block barrier draining ONLY lgkmcnt (keeps global loads in flight).
__device__ inline void barrier_lgkm() {
  asm volatile("s_waitcnt lgkmcnt(0)\n\ts_barrier" ::: "memory");
}

__device__ inline void band_coef(int k, float& a1, float& a2, float& b0) {
  float fc = 80.0f * exp2f((float)k * (6.64385618977472436f / 23.0f));
  float w = 2.0f * PI_F * fc / FS_F;
  float r = expf(-PI_F * fc / (10.0f * FS_F));
  a1 = -2.0f * r * cosf(w);
  a2 = r * r;
  b0 = 1.0f - r;
}

// ---- data-independent body tables (verified bit-exact vs in-body compute) --
__device__ inline void gen_tables(float* __restrict__ tabs, int W) {
  if (W >= 120) return;
  const int j = W / 5, sub = W % 5;
  float A1, A2, B0;
  band_coef(j, A1, A2, B0);
  if (sub == 0) *(float4*)&tabs[j * 4] = make_float4(A1, A2, B0, 0.f);
  float Q00 = -A1, Q01 = -A2, Q10 = 1.f, Q11 = 0.f;
#pragma unroll
  for (int sq = 0; sq < 2; ++sq) {
    float n00 = fmaf(Q00, Q00, Q01 * Q10);
    float n01 = fmaf(Q00, Q01, Q01 * Q11);
    float n10 = fmaf(Q10, Q00, Q11 * Q10);
    float n11 = fmaf(Q10, Q01, Q11 * Q11);
    Q00 = n00; Q01 = n01; Q10 = n10; Q11 = n11;
  }
  float K00 = Q00, K01 = Q01, K10 = Q10, K11 = Q11;
#pragma unroll
  for (int sq = 0; sq < 2; ++sq) {
    float n00 = fmaf(Q00, Q00, Q01 * Q10);
    float n01 = fmaf(Q00, Q01, Q01 * Q11);
    float n10 = fmaf(Q10, Q00, Q11 * Q10);
    float n11 = fmaf(Q10, Q01, Q11 * Q11);
    Q00 = n00; Q01 = n01; Q10 = n10; Q11 = n11;
  }
  float L00[7], L01[7], L10[7], L11[7];
  L00[0] = fmaf(Q00, K00, Q01 * K10);
  L01[0] = fmaf(Q00, K01, Q01 * K11);
  L10[0] = fmaf(Q10, K00, Q11 * K10);
  L11[0] = fmaf(Q10, K01, Q11 * K11);
#pragma unroll
  for (int k = 0; k < 6; ++k) {
    float s00 = fmaf(L00[k], L00[k], L01[k] * L10[k]);
    float s01 = fmaf(L00[k], L01[k], L01[k] * L11[k]);
    float s10 = fmaf(L10[k], L00[k], L11[k] * L10[k]);
    float s11 = fmaf(L10[k], L01[k], L11[k] * L11[k]);
    L00[k + 1] = s00; L01[k + 1] = s01; L10[k + 1] = s10; L11[k + 1] = s11;
  }
  if (sub == 0) {
#pragma unroll
    for (int k = 0; k < 6; ++k)
      *(float4*)&tabs[96 + (k * 24 + j) * 4] =
          make_float4(L00[k], L01[k], L10[k], L11[k]);
    *(float4*)&tabs[672 + j * 4] = make_float4(L00[6], L01[6], L10[6], L11[6]);
  }
  int l0 = sub * 13, l1 = l0 + 13;
  if (l1 > 64) l1 = 64;
  for (int l = l0; l < l1; ++l) {
    float R00 = 1.f, R01 = 0.f, R10 = 0.f, R11 = 1.f;
#pragma unroll
    for (int bit = 0; bit < 6; ++bit) {
      if ((l >> bit) & 1) {
        float n00 = fmaf(L00[bit], R00, L01[bit] * R10);
        float n01 = fmaf(L00[bit], R01, L01[bit] * R11);
        float n10 = fmaf(L10[bit], R00, L11[bit] * R10);
        float n11 = fmaf(L10[bit], R01, L11[bit] * R11);
        R00 = n00; R01 = n01; R10 = n10; R11 = n11;
      }
    }
    *(float4*)&tabs[768 + (j * 64 + l) * 4] = make_float4(R00, R01, R10, R11);
  }
}

// ---- preLP scan context (prologue: 4-wave, 8 samples/thread) ----
struct SCtx {
  float scale, c;
  float m1, m2, m4, m8, m16, m32, c512, c2048, c8lane, cgk;
  float vrun;
  float* lws;
};

// guarded 8-float load (two float4) at global index g0
__device__ inline void ld2(const float* __restrict__ p, int g0, float4& a,
                           float4& b) {
  a = make_float4(0.f, 0.f, 0.f, 0.f);
  b = make_float4(0.f, 0.f, 0.f, 0.f);
  if (g0 >= 0 && g0 + 3 < NSAMP) a = *(const float4*)&p[g0];
  if (g0 + 4 >= 0 && g0 + 7 < NSAMP) b = *(const float4*)&p[g0 + 4];
}

// One segment of the block-wide preLP scan (R3-proven math, bit-exact).
// Data pre-loaded by caller; destination = flat xall[sg*2048 + 8t).
// Thread-consecutive float4 stores -> conflict-free. lgkm-only barriers keep
// the caller's pipelined global loads in flight.
__device__ inline void scan_seg_flat(SCtx& SC, float* xall, int sg, bool write,
                                     int t, float4 xa, float4 xb) {
  const int lane = t & 63, wid = t >> 6;
  barrier_lgkm();  // protect lws reuse from previous call's readers
  const float c = SC.c, scale = SC.scale;
  float S = 0.0f;
  S = fmaf(c, S, scale * xa.x); S = fmaf(c, S, scale * xa.y);
  S = fmaf(c, S, scale * xa.z); S = fmaf(c, S, scale * xa.w);
  S = fmaf(c, S, scale * xb.x); S = fmaf(c, S, scale * xb.y);
  S = fmaf(c, S, scale * xb.z); S = fmaf(c, S, scale * xb.w);
  float Sw = S, u;
  u = __shfl_up(Sw, 1);  if (lane >= 1)  Sw = fmaf(SC.m1, u, Sw);
  u = __shfl_up(Sw, 2);  if (lane >= 2)  Sw = fmaf(SC.m2, u, Sw);
  u = __shfl_up(Sw, 4);  if (lane >= 4)  Sw = fmaf(SC.m4, u, Sw);
  u = __shfl_up(Sw, 8);  if (lane >= 8)  Sw = fmaf(SC.m8, u, Sw);
  u = __shfl_up(Sw, 16); if (lane >= 16) Sw = fmaf(SC.m16, u, Sw);
  u = __shfl_up(Sw, 32); if (lane >= 32) Sw = fmaf(SC.m32, u, Sw);
  if (lane == 63) SC.lws[wid] = Sw;
  barrier_lgkm();
  float a0 = SC.lws[0], a1w = SC.lws[1], a2w = SC.lws[2], a3w = SC.lws[3];
  float carry = (wid == 1)   ? a0
                : (wid == 2) ? fmaf(SC.c512, a0, a1w)
                : (wid == 3) ? fmaf(SC.c512, fmaf(SC.c512, a0, a1w), a2w)
                             : 0.0f;
  float Sprev = __shfl_up(Sw, 1);
  float Sex = (lane == 0) ? 0.0f : Sprev;
  Sex = fmaf(SC.c8lane, carry, Sex);
  float v = fmaf(SC.cgk, SC.vrun, Sex);
  float4 ya, yb;
  v = fmaf(c, v, scale * xa.x); ya.x = v;
  v = fmaf(c, v, scale * xa.y); ya.y = v;
  v = fmaf(c, v, scale * xa.z); ya.z = v;
  v = fmaf(c, v, scale * xa.w); ya.w = v;
  v = fmaf(c, v, scale * xb.x); yb.x = v;
  v = fmaf(c, v, scale * xb.y); yb.y = v;
  v = fmaf(c, v, scale * xb.z); yb.z = v;
  v = fmaf(c, v, scale * xb.w); yb.w = v;
  if (write) {
    int o = (sg << 11) + 8 * t;
    *(float4*)&xall[o] = ya;
    *(float4*)&xall[o + 4] = yb;
  }
  float tS = fmaf(SC.c512, fmaf(SC.c512, fmaf(SC.c512, a0, a1w), a2w), a3w);
  SC.vrun = fmaf(SC.c2048, SC.vrun, tS);
}

// ---- single-wave KS recurrence (wave 0), barrier-free, x fully in LDS ----
template <int KNUM>
__device__ void ks_wave0(float* __restrict__ yg, const float* xall, int lane,
                         int C, float c0w, float c1w, float c2w, int s1,
                         int n0, int end, int span) {
  const int lq1 = (C - 1) - (KNUM - 1) * 64;
  const int W = n0 - s1;
  float yp[KNUM], xC[KNUM], xN[KNUM];
  float p1 = 0.f, p2 = 0.f;
#pragma unroll
  for (int k = 0; k < KNUM; ++k) {
    yp[k] = 0.f;
    xC[k] = xall[lane + (k << 6)];
    xN[k] = xall[C + lane + (k << 6)];
  }
  int rel = 0;
  while (rel + C <= W) {  // lean warm-up (no stores)
    float b2v[KNUM], b3v[KNUM];
    b2v[0] = shr1(yp[0], p1);
#pragma unroll
    for (int k = 1; k < KNUM; ++k) b2v[k] = shr1(yp[k], ror1(yp[k - 1]));
    b3v[0] = shr1(b2v[0], p2);
#pragma unroll
    for (int k = 1; k < KNUM; ++k) b3v[k] = shr1(b2v[k], ror1(b2v[k - 1]));
    float p1n = rlv(yp[KNUM - 1], lq1);
    float p2n = rlv(b2v[KNUM - 1], lq1);
#pragma unroll
    for (int k = 0; k < KNUM; ++k)
      yp[k] = fmaf(c0w, yp[k], fmaf(c2w, b3v[k], fmaf(c1w, b2v[k], xC[k])));
    p1 = p1n;
    p2 = p2n;
    int r2 = rel + 2 * C;
    if (r2 < span) {
      const float* xp = &xall[r2 + lane];
#pragma unroll
      for (int k = 0; k < KNUM; ++k) {
        xC[k] = xN[k];
        xN[k] = xp[k << 6];
      }
    } else {
#pragma unroll
      for (int k = 0; k < KNUM; ++k) xC[k] = xN[k];
    }
    rel += C;
  }
  while (rel < span) {  // live region (stores)
    float b2v[KNUM], b3v[KNUM];
    b2v[0] = shr1(yp[0], p1);
#pragma unroll
    for (int k = 1; k < KNUM; ++k) b2v[k] = shr1(yp[k], ror1(yp[k - 1]));
    b3v[0] = shr1(b2v[0], p2);
#pragma unroll
    for (int k = 1; k < KNUM; ++k) b3v[k] = shr1(b2v[k], ror1(b2v[k - 1]));
    float p1n = rlv(yp[KNUM - 1], lq1);
    float p2n = rlv(b2v[KNUM - 1], lq1);
#pragma unroll
    for (int k = 0; k < KNUM; ++k)
      yp[k] = fmaf(c0w, yp[k], fmaf(c2w, b3v[k], fmaf(c1w, b2v[k], xC[k])));
    p1 = p1n;
    p2 = p2n;
#pragma unroll
    for (int k = 0; k < KNUM; ++k) {
      int i = lane + (k << 6);
      int n = s1 + rel + i;
      bool okl = (k < KNUM - 1) || (lane <= lq1);
      if (okl && n >= n0 && n < end) yg[n] = yp[k];
    }
    int r2 = rel + 2 * C;
    if (r2 < span) {
      const float* xp = &xall[r2 + lane];
#pragma unroll
      for (int k = 0; k < KNUM; ++k) {
        xC[k] = xN[k];
        xN[k] = xp[k << 6];
      }
    } else {
#pragma unroll
      for (int k = 0; k < KNUM; ++k) xC[k] = xN[k];
    }
    rel += C;
  }
}

// ---- KS phase: (1) block-wide pipelined preLP scan of the WHOLE span into
// LDS (R3 scan math, static register pipeline, no scratch), (2) wave0
// free-runs the recurrence with zero barriers; waves 2-3 generate tables. ----
__device__ inline void ks_phase(int b, int q, const BParams& P,
                                const float* __restrict__ exc, float scale0,
                                float* __restrict__ buf1, float* xall,
                                float* lws, float* tabs, int t) {
  const int C = P.Di;
  const int n0 = q << 10;
  float lg = -logf(P.g);
  int Wp = (int)ceilf(10.5f / fmaxf(lg, 1e-6f));
  if (Wp > 64) Wp = 64;
  if (Wp < 4) Wp = 4;
  int W = Wp * C;
  if (W > n0) W = n0;
  W = (W + 3) & ~3;
  const int s1 = n0 - W;
  const int span = W + T1;
  const int end = n0 + T1;
  const int NSG = (span + 2047) >> 11;  // segments covering span, <= 16
  float* yg = buf1 + (size_t)b * NSAMP;
  const float* xg = exc + (size_t)b * NSAMP;

  SCtx SC;
  SC.c = 1.0f - P.alpha;
  SC.scale = scale0 * P.alpha;
  {
    float c = SC.c;
    float c2v = c * c, c4 = c2v * c2v, c8 = c4 * c4;
    SC.m1 = c8;
    SC.m2 = SC.m1 * SC.m1;
    SC.m4 = SC.m2 * SC.m2;
    SC.m8 = SC.m4 * SC.m4;
    SC.m16 = SC.m8 * SC.m8;
    SC.m32 = SC.m16 * SC.m16;
    SC.c512 = SC.m32 * SC.m32;
    float c1024 = SC.c512 * SC.c512;
    SC.c2048 = c1024 * c1024;
    float l2c = log2f(c);
    SC.c8lane = exp2f((float)(8 * (t & 63)) * l2c);
    SC.cgk = exp2f((float)(8 * t) * l2c);
  }
  SC.vrun = 0.0f;
  SC.lws = lws;

  // pipelined scan: iteration si consumes segment si-1 (si=0: vrun pre-warm
  // [s1-2048, s1), totals only). 3 segments of loads in flight, all named
  // registers (no runtime-indexed arrays -> no scratch).
  float4 xa, xb, na, nb;
  float4 ta = make_float4(0.f, 0.f, 0.f, 0.f);
  float4 tb = make_float4(0.f, 0.f, 0.f, 0.f);
  ld2(xg, s1 - 2048 + 8 * t, xa, xb);
  ld2(xg, s1 + 8 * t, na, nb);
  for (int si = 0; si <= NSG; ++si) {
    if (si + 2 <= NSG) ld2(xg, s1 + ((si + 1) << 11) + 8 * t, ta, tb);
    scan_seg_flat(SC, xall, si - 1, si > 0, t, xa, xb);
    xa = na; xb = nb; na = ta; nb = tb;
  }
  // zero-pad [NSG*2048, +768) so KS prefetch over-reads are bounded zeros
  if (4 * t < 768) {
    *(float4*)&xall[(NSG << 11) + 4 * t] = make_float4(0.f, 0.f, 0.f, 0.f);
  }
  __syncthreads();

  // ---- KS on wave 0 (no barriers); tables on waves 2-3 ----
  const float c0w = P.g * (1.0f - P.s) * (1.0f - P.fr);
  const float c1w = P.g * ((1.0f - P.s) * P.fr + P.s * (1.0f - P.fr));
  const float c2w = P.g * P.s * P.fr;
  const int lane = t & 63, wid = t >> 6;
  if (wid == 0) {
    switch ((C + 63) >> 6) {
      case 2:  ks_wave0<2>(yg, xall, lane, C, c0w, c1w, c2w, s1, n0, end, span); break;
      case 3:  ks_wave0<3>(yg, xall, lane, C, c0w, c1w, c2w, s1, n0, end, span); break;
      case 4:  ks_wave0<4>(yg, xall, lane, C, c0w, c1w, c2w, s1, n0, end, span); break;
      case 5:  ks_wave0<5>(yg, xall, lane, C, c0w, c1w, c2w, s1, n0, end, span); break;
      case 6:  ks_wave0<6>(yg, xall, lane, C, c0w, c1w, c2w, s1, n0, end, span); break;
      case 7:  ks_wave0<7>(yg, xall, lane, C, c0w, c1w, c2w, s1, n0, end, span); break;
      case 8:  ks_wave0<8>(yg, xall, lane, C, c0w, c1w, c2w, s1, n0, end, span); break;
      case 9:  ks_wave0<9>(yg, xall, lane, C, c0w, c1w, c2w, s1, n0, end, span); break;
      case 10: ks_wave0<10>(yg, xall, lane, C, c0w, c1w, c2w, s1, n0, end, span); break;
      case 11: ks_wave0<11>(yg, xall, lane, C, c0w, c1w, c2w, s1, n0, end, span); break;
      default: ks_wave0<12>(yg, xall, lane, C, c0w, c1w, c2w, s1, n0, end, span); break;
    }
  } else if (wid >= 2) {
    gen_tables(tabs, (wid - 2) * 64 + lane);
  }
}

// One-pole scan over [s2, s2+nt*2048) from global into LDS sl[n-s2], reads
// clamped at `lim`.
__device__ inline void lpc_lds(const float* __restrict__ xg,
                               float* __restrict__ sl, int s2, int nt, int lim,
                               float scale, float c, int t, float* lws) {
  const int lane = t & 63, wid = t >> 6;
  float c2v = c * c, c4 = c2v * c2v, c8 = c4 * c4;
  float m1 = c8, m2 = m1 * m1, m4 = m2 * m2, m8 = m4 * m4, m16 = m8 * m8,
        m32 = m16 * m16;
  float c512 = m32 * m32;
  float c2048 = c512 * c512;
  c2048 *= c2048;
  float l2c = log2f(c);
  float c8lane = exp2f((float)(8 * lane) * l2c);
  float cgk = exp2f((float)(8 * t) * l2c);
  float vrun = 0.0f;
  for (int tile = 0; tile < nt; ++tile) {
    __syncthreads();
    int g0 = s2 + (tile << 11) + 8 * t;
    float4 xa = make_float4(0.f, 0.f, 0.f, 0.f);
    float4 xb = make_float4(0.f, 0.f, 0.f, 0.f);
    if (g0 + 3 < lim) xa = *(const float4*)&xg[g0];
    if (g0 + 7 < lim) xb = *(const float4*)&xg[g0 + 4];
    float S = 0.0f;
    S = fmaf(c, S, scale * xa.x); S = fmaf(c, S, scale * xa.y);
    S = fmaf(c, S, scale * xa.z); S = fmaf(c, S, scale * xa.w);
    S = fmaf(c, S, scale * xb.x); S = fmaf(c, S, scale * xb.y);
    S = fmaf(c, S, scale * xb.z); S = fmaf(c, S, scale * xb.w);
    float Sw = S, u;
    u = __shfl_up(Sw, 1);  if (lane >= 1)  Sw = fmaf(m1, u, Sw);
    u = __shfl_up(Sw, 2);  if (lane >= 2)  Sw = fmaf(m2, u, Sw);
    u = __shfl_up(Sw, 4);  if (lane >= 4)  Sw = fmaf(m4, u, Sw);
    u = __shfl_up(Sw, 8);  if (lane >= 8)  Sw = fmaf(m8, u, Sw);
    u = __shfl_up(Sw, 16); if (lane >= 16) Sw = fmaf(m16, u, Sw);
    u = __shfl_up(Sw, 32); if (lane >= 32) Sw = fmaf(m32, u, Sw);
    if (lane == 63) lws[wid] = Sw;
    __syncthreads();
    float a0 = lws[0], a1w = lws[1], a2w = lws[2], a3w = lws[3];
    float carry = (wid == 1)   ? a0
                  : (wid == 2) ? fmaf(c512, a0, a1w)
                  : (wid == 3) ? fmaf(c512, fmaf(c512, a0, a1w), a2w)
                               : 0.0f;
    float Sprev = __shfl_up(Sw, 1);
    float Sex = (lane == 0) ? 0.0f : Sprev;
    Sex = fmaf(c8lane, carry, Sex);
    float v = fmaf(cgk, vrun, Sex);
    int o = g0 - s2;
    float4 ya, yb;
    v = fmaf(c, v, scale * xa.x); ya.x = v;
    v = fmaf(c, v, scale * xa.y); ya.y = v;
    v = fmaf(c, v, scale * xa.z); ya.z = v;
    v = fmaf(c, v, scale * xa.w); ya.w = v;
    v = fmaf(c, v, scale * xb.x); yb.x = v;
    v = fmaf(c, v, scale * xb.y); yb.y = v;
    v = fmaf(c, v, scale * xb.z); yb.z = v;
    v = fmaf(c, v, scale * xb.w); yb.w = v;
    *(float4*)&sl[o] = ya;
    *(float4*)&sl[o + 4] = yb;
    float tS = fmaf(c512, fmaf(c512, fmaf(c512, a0, a1w), a2w), a3w);
    vrun = fmaf(c2048, vrun, tS);
  }
}

// ---- body phase, T2=1024; matrix powers loaded from LDS tables ----
__device__ inline void body_phase(int b, int q, const BParams& P,
                                  const float* __restrict__ gains,
                                  const float* __restrict__ buf1,
                                  float* __restrict__ out, float* sl,
                                  float* lws, float (*lc0)[8],
                                  float (*lc1)[8], const float* tabs, int t) {
  const int lane = t & 63, wid = t >> 6;
  const int n0 = q << 10;
  const int base = n0 - 4096;
  int s2 = base - 256;
  if (s2 < 0) s2 = 0;
  const int end = n0 + 1024;
  const int nt = (end - s2 + 2047) >> 11;  // <= 3

  lpc_lds(buf1 + (size_t)b * NSAMP, sl, s2, nt, end, P.alpha_p,
          1.0f - P.alpha_p, t, lws);
  __syncthreads();

  const float* bandcL = tabs;
  const float* QlevL = tabs + 96;
  const float* QwL = tabs + 672;
  const float* RtabL = tabs + 768;

  const int tb = base + 20 * t;
  float4 acc[5];
#pragma unroll
  for (int i = 0; i < 5; ++i) acc[i] = make_float4(0.f, 0.f, 0.f, 0.f);

  for (int g = 0; g < 3; ++g) {
    float A1[8], A2[8], B0[8], GN[8];
#pragma unroll
    for (int j = 0; j < 8; ++j) {
      int k = g * 8 + j;
      float4 bc = *(const float4*)&bandcL[k * 4];
      A1[j] = bc.x; A2[j] = bc.y; B0[j] = bc.z;
      GN[j] = gains[k];
    }
    float cv0[8], cv1[8];
#pragma unroll
    for (int j = 0; j < 8; ++j) cv0[j] = cv1[j] = 0.f;
    for (int i = 0; i < 5; ++i) {
      int n = tb + 4 * i;
      float4 xv = make_float4(0.f, 0.f, 0.f, 0.f);
      if (n >= 0) xv = *(const float4*)&sl[n - s2];
#pragma unroll
      for (int e = 0; e < 4; ++e) {
        float xi = e == 0 ? xv.x : e == 1 ? xv.y : e == 2 ? xv.z : xv.w;
#pragma unroll
        for (int j = 0; j < 8; ++j) {
          float nc = fmaf(B0[j], xi, -fmaf(A1[j], cv0[j], A2[j] * cv1[j]));
          cv1[j] = cv0[j];
          cv0[j] = nc;
        }
      }
    }
    int kl = 0;
    for (int off = 1; off <= 32; off <<= 1, ++kl) {
      float q00[8], q01[8], q10[8], q11[8];
#pragma unroll
      for (int j = 0; j < 8; ++j) {
        float4 qv = *(const float4*)&QlevL[(kl * 24 + g * 8 + j) * 4];
        q00[j] = qv.x; q01[j] = qv.y; q10[j] = qv.z; q11[j] = qv.w;
      }
#pragma unroll
      for (int j = 0; j < 8; ++j) {
        float u0 = __shfl_up(cv0[j], off);
        float u1 = __shfl_up(cv1[j], off);
        if (lane >= off) {
          float nc0 = fmaf(q00[j], u0, fmaf(q01[j], u1, cv0[j]));
          float nc1 = fmaf(q10[j], u0, fmaf(q11[j], u1, cv1[j]));
          cv0[j] = nc0;
          cv1[j] = nc1;
        }
      }
    }
    __syncthreads();
    if (lane == 63) {
#pragma unroll
      for (int j = 0; j < 8; ++j) {
        lc0[wid][j] = cv0[j];
        lc1[wid][j] = cv1[j];
      }
    }
    __syncthreads();
    float qw00[8], qw01[8], qw10[8], qw11[8];
#pragma unroll
    for (int j = 0; j < 8; ++j) {
      float4 qv = *(const float4*)&QwL[(g * 8 + j) * 4];
      qw00[j] = qv.x; qw01[j] = qv.y; qw10[j] = qv.z; qw11[j] = qv.w;
    }
    float car0[8], car1[8];
#pragma unroll
    for (int j = 0; j < 8; ++j) car0[j] = car1[j] = 0.f;
    for (int v = 0; v < wid; ++v) {
#pragma unroll
      for (int j = 0; j < 8; ++j) {
        float n0c = fmaf(qw00[j], car0[j], fmaf(qw01[j], car1[j], lc0[v][j]));
        float n1c = fmaf(qw10[j], car0[j], fmaf(qw11[j], car1[j], lc1[v][j]));
        car0[j] = n0c;
        car1[j] = n1c;
      }
    }
    float y1[8], y2[8];
#pragma unroll
    for (int j = 0; j < 8; ++j) {
      float4 rv = *(const float4*)&RtabL[((g * 8 + j) * 64 + lane) * 4];
      float e0 = __shfl_up(cv0[j], 1);
      float e1 = __shfl_up(cv1[j], 1);
      if (lane == 0) { e0 = 0.f; e1 = 0.f; }
      y1[j] = fmaf(rv.x, car0[j], fmaf(rv.y, car1[j], e0));
      y2[j] = fmaf(rv.z, car0[j], fmaf(rv.w, car1[j], e1));
    }
    if (tb + 20 > n0) {
      for (int i = 0; i < 5; ++i) {
        float4 xv = *(const float4*)&sl[tb - s2 + 4 * i];
        float4 ov = acc[i];
#pragma unroll
        for (int e = 0; e < 4; ++e) {
          float xi = e == 0 ? xv.x : e == 1 ? xv.y : e == 2 ? xv.z : xv.w;
          float a = 0.f;
#pragma unroll
          for (int j = 0; j < 8; ++j) {
            float yv = fmaf(B0[j], xi, -fmaf(A1[j], y1[j], A2[j] * y2[j]));
            y2[j] = y1[j];
            y1[j] = yv;
            a = fmaf(GN[j], yv, a);
          }
          if (e == 0) ov.x += a;
          else if (e == 1) ov.y += a;
          else if (e == 2) ov.z += a;
          else ov.w += a;
        }
        acc[i] = ov;
      }
    }
  }
  if (tb + 20 > n0) {
    float* outb = out + (size_t)b * NSAMP;
#pragma unroll
    for (int i = 0; i < 5; ++i) {
      int n = tb + 4 * i;
      if (n >= n0) *(float4*)&outb[n] = acc[i];
    }
  }
}

// ======== single kernel, 256 blocks; dynamic LDS 161920 B ========
__global__ void __launch_bounds__(256, 1) synth_all(
    const float* __restrict__ exc, const float* __restrict__ pitch,
    const float* __restrict__ w1, const float* __restrict__ b1,
    const float* __restrict__ w2, const float* __restrict__ b2,
    const float* __restrict__ eg, const float* __restrict__ gains,
    float* __restrict__ buf1, int* __restrict__ flags,
    float* __restrict__ out) {
  extern __shared__ float smem[];
  const int blk = blockIdx.x;
  const int b = blk >> 5, q = blk & 31;
  const int t = threadIdx.x;

  BParams P = compute_params(b, pitch, w1, b1, w2, b2);
  if (blk == 0 && t < 64) {
    int bb = (t < 8) ? t : 0;
    BParams Q = compute_params(bb, pitch, w1, b1, w2, b2);
    float slc = 0.f, slm = 0.f, slp = 0.f;
    for (int i = 0; i < 8; ++i) {
      slc += rlv(Q.lc, i);
      slm += rlv(Q.lm, i);
      slp += rlv(Q.lp, i);
    }
    if (t == 0) {
      out[8 * NSAMP + 0] = slc / 8.0f;
      out[8 * NSAMP + 1] = slm / 8.0f;
      out[8 * NSAMP + 2] = slp / 8.0f;
    }
  }

  // ---- phase 1: KS slice q (writes buf1[n0, n0+1024)); tables generated ----
  ks_phase(b, q, P, exc, eg[0], buf1, smem, smem + LWS_OFF, smem + TABS_OFF, t);
  __syncthreads();  // drain wave0's global stores + table writes

  // ---- handoff: publish own flag, wait for same-batch predecessors ----
  const int n0 = q << 10;
  int s2 = n0 - 4096 - 256;
  if (s2 < 0) s2 = 0;
  const int qlo = s2 >> 10;
  if (t == 0) {
    __hip_atomic_store(&flags[blk], FLAG_MAGIC, __ATOMIC_RELEASE,
                       __HIP_MEMORY_SCOPE_AGENT);
    for (int f = qlo; f < q; ++f) {
      while (__hip_atomic_load(&flags[b * 32 + f], __ATOMIC_ACQUIRE,
                               __HIP_MEMORY_SCOPE_AGENT) != FLAG_MAGIC) {
        __builtin_amdgcn_s_sleep(8);
      }
    }
  }
  __syncthreads();

  // ---- phase 2: body slice q (xall region reused; tables persist) ----
  body_phase(b, q, P, gains, buf1, out, smem, smem + 6144,
             (float(*)[8])(smem + 6152), (float(*)[8])(smem + 6184),
             smem + TABS_OFF, t);
}

extern "C" void kernel_launch(void* const* d_in, const int* in_sizes, int n_in,
                              void* d_out, int out_size, void* d_ws, size_t ws_size,
                              hipStream_t stream) {
  const float* exc = (const float*)d_in[0];
  const float* pitch = (const float*)d_in[1];
  const float* w1 = (const float*)d_in[2];
  const float* b1 = (const float*)d_in[3];
  const float* w2 = (const float*)d_in[4];
  const float* b2 = (const float*)d_in[5];
  const float* eg = (const float*)d_in[6];
  const float* bg = (const float*)d_in[7];
  float* out = (float*)d_out;
  float* buf1 = (float*)d_ws;             // 8*NSAMP floats (KS output)
  int* flags = (int*)(buf1 + 8 * NSAMP);  // 256 flags (poison != MAGIC)

  static int lds_set = 0;
  if (!lds_set) {
    hipFuncSetAttribute(reinterpret_cast<const void*>(synth_all),
                        hipFuncAttributeMaxDynamicSharedMemorySize,
                        SMEM_FLOATS * 4);
    lds_set = 1;
  }
  hipLaunchKernelGGL(synth_all, dim3(256), dim3(256), SMEM_FLOATS * 4, stream,
                     exc, pitch, w1, b1, w2, b2, eg, bg, buf1, flags, out);
}